// Round 1
// 313.661 us; speedup vs baseline: 1.0284x; 1.0284x over previous
//
#include <hip/hip_runtime.h>
#include <hip/hip_bf16.h>

// FieldDecoder: B=16, 64x64 tokens, DO=768, kernel 16x16, stride 8, field 512x512
#define DIM      768
#define NPATCH   4096
#define BATCH    16
#define MROWS    65536
#define NCOLS    256

typedef __attribute__((ext_vector_type(8))) short bf16x8;
typedef __attribute__((ext_vector_type(4))) float f32x4;

static __device__ __forceinline__ unsigned short f2bf(float f) {
    union { float f; unsigned int u; } v; v.f = f;
    unsigned int u = v.u;
    return (unsigned short)((u + 0x7FFFu + ((u >> 16) & 1u)) >> 16);
}
static __device__ __forceinline__ float bf2f(unsigned int u16) {
    union { unsigned int i; float f; } x; x.i = u16 << 16; return x.f;
}
static __device__ __forceinline__ bf16x8 pack_bf8(float4 a, float4 b) {
    union { bf16x8 v; unsigned int u[4]; } r;
    r.u[0] = (unsigned)f2bf(a.x) | ((unsigned)f2bf(a.y) << 16);
    r.u[1] = (unsigned)f2bf(a.z) | ((unsigned)f2bf(a.w) << 16);
    r.u[2] = (unsigned)f2bf(b.x) | ((unsigned)f2bf(b.y) << 16);
    r.u[3] = (unsigned)f2bf(b.z) | ((unsigned)f2bf(b.w) << 16);
    return r.v;
}

// async 16B global -> LDS (linear dest: uniform base + lane*16; no swizzle -> legal)
static __device__ __forceinline__ void gload16(const void* g, void* l) {
    __builtin_amdgcn_global_load_lds((const __attribute__((address_space(1))) void*)g,
                                     (__attribute__((address_space(3))) void*)l, 16, 0, 0);
}

// ---------------- kernel 0: pack W into MFMA B-fragment order ----------------
// Bfrag[((kk*16 + j)*64 + lane)*8 + e] = bf16( W[(j*16 + (lane&15))*768 + kk*32 + (lane>>4)*8 + e] )
__global__ void wpack_kernel(const float* __restrict__ w, unsigned short* __restrict__ wf) {
    const int t    = blockIdx.x * blockDim.x + threadIdx.x;   // 0..24575
    const int lane = t & 63;
    const int j    = (t >> 6) & 15;
    const int kk   = t >> 10;                                 // 0..23
    const int n    = j * 16 + (lane & 15);
    const int k    = kk * 32 + (lane >> 4) * 8;
    const float* src = w + (size_t)n * DIM + k;
    float4 v0 = *(const float4*)src;
    float4 v1 = *(const float4*)(src + 4);
    union { bf16x8 v; uint4 q; } o;
    o.v = pack_bf8(v0, v1);
    *(uint4*)(wf + (size_t)t * 8) = o.q;
}

// ---------------- kernel 1: GEMM  proj[M,256] = A[M,768](fp32->bf16) x W^T ----------------
// 2-phase pipeline (T3-minimum): 12 phases of K=64; B staged async via global_load_lds into
// 2 x 32 KB LDS double-buffer (issued BEFORE compute of current phase, drained by the one
// __syncthreads per phase); A register-double-buffered one phase ahead (zero phase-start stall).
// Epilogue transpose XOR-swizzled ((j^quad) col group) -> conflict-free b16 writes.
__global__ __launch_bounds__(256, 2) void gemm_kernel(const float* __restrict__ A,
                                                      const unsigned short* __restrict__ Bf,
                                                      unsigned short* __restrict__ Cb) {
    __shared__ unsigned short smem[128 * 256];   // 64 KB: 2 x 32 KB B dbuf | epilogue transpose

    const int tid  = threadIdx.x;
    const int w    = tid >> 6;
    const int lane = tid & 63;
    const int l15  = lane & 15;
    const int quad = lane >> 4;
    const int m0   = blockIdx.x * 128;

    f32x4 acc[2][16] = {};

    const float* a0 = A + (size_t)(m0 + w * 32 + l15) * DIM + quad * 8;
    const float* a1 = a0 + (size_t)16 * DIM;
    const uint4* gB = (const uint4*)Bf;

    // ---- prologue: stage phase 0 (async) + prefetch A phase 0 ----
    #pragma unroll
    for (int s = 0; s < 8; ++s)
        gload16(gB + s * 256 + tid, smem + (size_t)(s * 256 + tid) * 8);
    float4 rA[8];
    #pragma unroll
    for (int kk2 = 0; kk2 < 2; ++kk2) {
        rA[kk2 * 4 + 0] = *(const float4*)(a0 + kk2 * 32);
        rA[kk2 * 4 + 1] = *(const float4*)(a0 + kk2 * 32 + 4);
        rA[kk2 * 4 + 2] = *(const float4*)(a1 + kk2 * 32);
        rA[kk2 * 4 + 3] = *(const float4*)(a1 + kk2 * 32 + 4);
    }
    __syncthreads();                              // drains stage(0) + A(0)

    for (int t = 0; t < 12; ++t) {
        // pack current A (values ready after barrier) -> frees rA for next prefetch
        bf16x8 af[4];
        #pragma unroll
        for (int kk2 = 0; kk2 < 2; ++kk2) {
            af[kk2 * 2 + 0] = pack_bf8(rA[kk2 * 4 + 0], rA[kk2 * 4 + 1]);
            af[kk2 * 2 + 1] = pack_bf8(rA[kk2 * 4 + 2], rA[kk2 * 4 + 3]);
        }
        // issue next phase's B staging + A prefetch; both fly under this phase's compute
        if (t + 1 < 12) {
            const uint4* src = gB + (t + 1) * 2048;
            unsigned short* dstb = smem + ((t + 1) & 1) * 16384;
            #pragma unroll
            for (int s = 0; s < 8; ++s)
                gload16(src + s * 256 + tid, dstb + (size_t)(s * 256 + tid) * 8);
            const int col = (t + 1) * 64;
            #pragma unroll
            for (int kk2 = 0; kk2 < 2; ++kk2) {
                rA[kk2 * 4 + 0] = *(const float4*)(a0 + col + kk2 * 32);
                rA[kk2 * 4 + 1] = *(const float4*)(a0 + col + kk2 * 32 + 4);
                rA[kk2 * 4 + 2] = *(const float4*)(a1 + col + kk2 * 32);
                rA[kk2 * 4 + 3] = *(const float4*)(a1 + col + kk2 * 32 + 4);
            }
        }
        // compute phase t from buf[t&1] (conflict-free lane-contiguous ds_read_b128)
        const unsigned short* bbase = smem + (t & 1) * 16384;
        #pragma unroll
        for (int kk2 = 0; kk2 < 2; ++kk2) {
            #pragma unroll
            for (int j = 0; j < 16; ++j) {
                const bf16x8 b = *(const bf16x8*)(bbase + ((kk2 * 16 + j) * 64 + lane) * 8);
                acc[0][j] = __builtin_amdgcn_mfma_f32_16x16x32_bf16(af[kk2 * 2 + 0], b, acc[0][j], 0, 0, 0);
                acc[1][j] = __builtin_amdgcn_mfma_f32_16x16x32_bf16(af[kk2 * 2 + 1], b, acc[1][j], 0, 0, 0);
            }
        }
        __syncthreads();   // all reads of buf[t&1] done; stage(t+1)+A(t+1) drained (vmcnt 0)
    }

    // ---- epilogue: XOR-swizzled LDS transpose -> 512 B/row coalesced bf16 stores ----
    // write (row, col j*16+l15) at physical col group (j^quad): row stride 512 B == 0 mod 32
    // banks, so quad XOR spreads the 4 quads across all 32 banks (2 lanes/bank = free).
    #pragma unroll
    for (int i = 0; i < 2; ++i)
        #pragma unroll
        for (int j = 0; j < 16; ++j)
            #pragma unroll
            for (int rr = 0; rr < 4; ++rr)
                smem[(w * 32 + i * 16 + quad * 4 + rr) * 256 + ((j ^ quad) * 16 + l15)] =
                    f2bf(acc[i][j][rr]);
    __syncthreads();

    const int orow = tid >> 3;          // 0..31
    const int ou   = tid & 7;           // 8 lanes x 64 B = 512 B per row
    #pragma unroll
    for (int rb = 0; rb < 4; ++rb) {
        const int row = orow + rb * 32;
        const int rq  = (row >> 2) & 3;               // quad that wrote this row
        const unsigned short* srcrow = smem + row * 256;
        unsigned short* dst = Cb + (size_t)(m0 + row) * NCOLS + ou * 32;
        #pragma unroll
        for (int q = 0; q < 4; ++q) {
            const int off = (ou * 32 + q * 8) ^ (rq * 16);   // 16B-aligned inverse swizzle
            *(uint4*)(dst + q * 8) = *(const uint4*)(srcrow + off);
        }
    }
}

// ---------------- kernel 2: gather-mean, block per (batch, patch-row h) ----------------
// LDS staging with bank-rotated padded strides; inner compute via ds_read_b128 (4 per 8-pixel task).
#define CSTRG 280   // sCur row stride (shorts): 560 B -> lane bank-start 12*wg mod 32 (full spread)
#define PSTRG 152   // sPrevHi row stride: 304 B -> same rotation
__global__ __launch_bounds__(256, 2) void gather_kernel(const unsigned short* __restrict__ proj,
                                                        float* __restrict__ out) {
    __shared__ unsigned short sCur[64 * CSTRG];     // 35840 B
    __shared__ unsigned short sPrevHi[64 * PSTRG];  // 19456 B

    const int blk = blockIdx.x;          // b*64 + h
    const int b   = blk >> 6;
    const int h   = blk & 63;
    const int tid = threadIdx.x;
    const unsigned short* base = proj + (size_t)b * (NPATCH * NCOLS);

    const uint4* gCur = (const uint4*)(base + (size_t)h * 64 * 256);
    #pragma unroll
    for (int p = 0; p < 8; ++p) {
        const int i = tid + p * 256;     // 2048 uint4: patch = i>>5, q = i&31
        *(uint4*)(sCur + (i >> 5) * CSTRG + (i & 31) * 8) = gCur[i];
    }
    if (h > 0) {
        const uint4* gPrev = (const uint4*)(base + (size_t)(h - 1) * 64 * 256);
        #pragma unroll
        for (int p = 0; p < 4; ++p) {
            const int i = tid + p * 256; // 1024 uint4: patch = i>>4, hi-half q = i&15
            *(uint4*)(sPrevHi + (i >> 4) * PSTRG + (i & 15) * 8) = gPrev[(i >> 4) * 32 + 16 + (i & 15)];
        }
    }
    __syncthreads();

    const float fch_base = (h == 0) ? 1.f : 0.5f;

    #pragma unroll
    for (int t = 0; t < 2; ++t) {
        const int task = tid + t * 256;  // r = task>>6 (wave-uniform), wg = lane
        const int r  = task >> 6;
        const int wg = task & 63;
        const int ph = h * 8 + r;

        float s[8] = {0.f, 0.f, 0.f, 0.f, 0.f, 0.f, 0.f, 0.f};
        auto addq = [&](uint4 v) {
            const unsigned int u[4] = {v.x, v.y, v.z, v.w};
            #pragma unroll
            for (int q = 0; q < 4; ++q) {
                s[2 * q]     += bf2f(u[q] & 0xFFFFu);
                s[2 * q + 1] += bf2f(u[q] >> 16);
            }
        };
        auto sumq = [&](uint4 v) -> float {
            const unsigned int u[4] = {v.x, v.y, v.z, v.w};
            float e = 0.f;
            #pragma unroll
            for (int q = 0; q < 4; ++q) e += bf2f(u[q] & 0xFFFFu) + bf2f(u[q] >> 16);
            return e;
        };

        addq(*(const uint4*)(sCur + wg * CSTRG + r * 16));                       // cur(h,wg) dw 0..7
        if (wg > 0) addq(*(const uint4*)(sCur + (wg - 1) * CSTRG + r * 16 + 8)); // cur(h,wg-1) dw 8..15
        if (h > 0) {
            addq(*(const uint4*)(sPrevHi + wg * PSTRG + r * 16));                // prev dh=r+8
            if (wg > 0) addq(*(const uint4*)(sPrevHi + (wg - 1) * PSTRG + r * 16 + 8));
        }
        if (wg == 63) {                   // w-clamp extras -> pixel 511 only
            s[7] += sumq(*(const uint4*)(sCur + 63 * CSTRG + r * 16 + 8));
            if (h > 0) s[7] += sumq(*(const uint4*)(sPrevHi + 63 * PSTRG + r * 16 + 8));
        }
        float fch = fch_base;
        if (ph == 511) {                  // h-clamp extras: dh 8..15 of cur patch-row 63
            fch = 0.1f;
            #pragma unroll 1
            for (int dh = 8; dh < 16; ++dh) {
                addq(*(const uint4*)(sCur + wg * CSTRG + dh * 16));
                if (wg > 0) addq(*(const uint4*)(sCur + (wg - 1) * CSTRG + dh * 16 + 8));
                if (wg == 63) s[7] += sumq(*(const uint4*)(sCur + 63 * CSTRG + dh * 16 + 8));
            }
        }

        const float fcw = (wg == 0) ? 1.f : 0.5f;
        float f7 = fcw;
        if (wg == 63) f7 = 0.1f;
        float* orow = out + ((size_t)(b * 512 + ph)) * 512 + wg * 8;
        *(float4*)orow       = make_float4(s[0] * fch * fcw, s[1] * fch * fcw,
                                           s[2] * fch * fcw, s[3] * fch * fcw);
        *(float4*)(orow + 4) = make_float4(s[4] * fch * fcw, s[5] * fch * fcw,
                                           s[6] * fch * fcw, s[7] * fch * f7);
    }
}

extern "C" void kernel_launch(void* const* d_in, const int* in_sizes, int n_in,
                              void* d_out, int out_size, void* d_ws, size_t ws_size,
                              hipStream_t stream) {
    const float* tgt    = (const float*)d_in[0];   // [16,4096,768] fp32
    const float* weight = (const float*)d_in[1];   // [16,16,768]  fp32
    float* out = (float*)d_out;                    // [16,512,512] fp32

    unsigned short* proj = (unsigned short*)d_ws;                                      // 32 MB bf16
    unsigned short* wf   = (unsigned short*)((char*)d_ws + (size_t)MROWS * NCOLS * 2); // +384 KB fragments

    wpack_kernel<<<96, 256, 0, stream>>>(weight, wf);               // 24576 threads
    gemm_kernel<<<MROWS / 128, 256, 0, stream>>>(tgt, wf, proj);    // 512 blocks
    gather_kernel<<<BATCH * 64, 256, 0, stream>>>(proj, out);       // 1024 blocks
}

// Round 2
// 313.501 us; speedup vs baseline: 1.0289x; 1.0005x over previous
//
#include <hip/hip_runtime.h>
#include <hip/hip_bf16.h>

// FieldDecoder: B=16, 64x64 tokens, DO=768, kernel 16x16, stride 8, field 512x512
#define DIM      768
#define NPATCH   4096
#define BATCH    16
#define MROWS    65536
#define NCOLS    256

typedef __attribute__((ext_vector_type(8))) short bf16x8;
typedef __attribute__((ext_vector_type(4))) float f32x4;

static __device__ __forceinline__ unsigned short f2bf(float f) {
    union { float f; unsigned int u; } v; v.f = f;
    unsigned int u = v.u;
    return (unsigned short)((u + 0x7FFFu + ((u >> 16) & 1u)) >> 16);
}
static __device__ __forceinline__ float bf2f(unsigned int u16) {
    union { unsigned int i; float f; } x; x.i = u16 << 16; return x.f;
}
static __device__ __forceinline__ bf16x8 pack_bf8(float4 a, float4 b) {
    union { bf16x8 v; unsigned int u[4]; } r;
    r.u[0] = (unsigned)f2bf(a.x) | ((unsigned)f2bf(a.y) << 16);
    r.u[1] = (unsigned)f2bf(a.z) | ((unsigned)f2bf(a.w) << 16);
    r.u[2] = (unsigned)f2bf(b.x) | ((unsigned)f2bf(b.y) << 16);
    r.u[3] = (unsigned)f2bf(b.z) | ((unsigned)f2bf(b.w) << 16);
    return r.v;
}

// async 16B global -> LDS (linear dest: uniform base + lane*16; no swizzle -> legal)
static __device__ __forceinline__ void gload16(const void* g, void* l) {
    __builtin_amdgcn_global_load_lds((const __attribute__((address_space(1))) void*)g,
                                     (__attribute__((address_space(3))) void*)l, 16, 0, 0);
}

// ---------------- kernel 0: pack W into MFMA B-fragment order ----------------
// Bfrag[((kk*16 + j)*64 + lane)*8 + e] = bf16( W[(j*16 + (lane&15))*768 + kk*32 + (lane>>4)*8 + e] )
__global__ void wpack_kernel(const float* __restrict__ w, unsigned short* __restrict__ wf) {
    const int t    = blockIdx.x * blockDim.x + threadIdx.x;   // 0..24575
    const int lane = t & 63;
    const int j    = (t >> 6) & 15;
    const int kk   = t >> 10;                                 // 0..23
    const int n    = j * 16 + (lane & 15);
    const int k    = kk * 32 + (lane >> 4) * 8;
    const float* src = w + (size_t)n * DIM + k;
    float4 v0 = *(const float4*)src;
    float4 v1 = *(const float4*)(src + 4);
    union { bf16x8 v; uint4 q; } o;
    o.v = pack_bf8(v0, v1);
    *(uint4*)(wf + (size_t)t * 8) = o.q;
}

// ---------------- kernel 1: GEMM  proj[M,256] = A[M,768](fp32->bf16) x W^T ----------------
// 2-buffer pipeline with COUNTED vmcnt (T4): per phase, issue B-stage(t+1) first (oldest),
// pack A(t) (compiler waits A only -> vmcnt(8), stage stays in flight), issue A(t+1),
// compute, then asm s_waitcnt vmcnt(8) + raw s_barrier -> the 8 A(t+1) loads cross the
// barrier in flight; the per-wave HBM queue NEVER drains to 0 in the main loop.
// Epilogue transpose XOR-swizzled ((j^quad) col group) -> conflict-free b16 writes.
__global__ __launch_bounds__(256, 2) void gemm_kernel(const float* __restrict__ A,
                                                      const unsigned short* __restrict__ Bf,
                                                      unsigned short* __restrict__ Cb) {
    __shared__ unsigned short smem[128 * 256];   // 64 KB: 2 x 32 KB B dbuf | epilogue transpose

    const int tid  = threadIdx.x;
    const int w    = tid >> 6;
    const int lane = tid & 63;
    const int l15  = lane & 15;
    const int quad = lane >> 4;
    const int m0   = blockIdx.x * 128;

    f32x4 acc[2][16] = {};

    const float* a0 = A + (size_t)(m0 + w * 32 + l15) * DIM + quad * 8;
    const float* a1 = a0 + (size_t)16 * DIM;
    const uint4* gB = (const uint4*)Bf;

    // ---- prologue: stage(0) first (oldest), then A(0); counted wait keeps A in flight ----
    #pragma unroll
    for (int s = 0; s < 8; ++s)
        gload16(gB + s * 256 + tid, smem + (size_t)(s * 256 + tid) * 8);
    float4 rA[8];
    #pragma unroll
    for (int kk2 = 0; kk2 < 2; ++kk2) {
        rA[kk2 * 4 + 0] = *(const float4*)(a0 + kk2 * 32);
        rA[kk2 * 4 + 1] = *(const float4*)(a0 + kk2 * 32 + 4);
        rA[kk2 * 4 + 2] = *(const float4*)(a1 + kk2 * 32);
        rA[kk2 * 4 + 3] = *(const float4*)(a1 + kk2 * 32 + 4);
    }
    asm volatile("s_waitcnt vmcnt(8)" ::: "memory");   // stage(0) landed; A(0) still flying
    __builtin_amdgcn_s_barrier();

    #pragma unroll
    for (int t = 0; t < 12; ++t) {
        // (1) issue next B staging FIRST - no dependency, maximize flight time
        if (t < 11) {
            const uint4* src = gB + (t + 1) * 2048;
            unsigned short* dstb = smem + ((t + 1) & 1) * 16384;
            #pragma unroll
            for (int s = 0; s < 8; ++s)
                gload16(src + s * 256 + tid, dstb + (size_t)(s * 256 + tid) * 8);
        }
        // (2) pack current A: compiler waits only the 8 A-loads (stage is younger -> stays)
        bf16x8 af[4];
        #pragma unroll
        for (int kk2 = 0; kk2 < 2; ++kk2) {
            af[kk2 * 2 + 0] = pack_bf8(rA[kk2 * 4 + 0], rA[kk2 * 4 + 1]);
            af[kk2 * 2 + 1] = pack_bf8(rA[kk2 * 4 + 2], rA[kk2 * 4 + 3]);
        }
        // (3) issue next A prefetch (youngest; will cross the barrier in flight)
        if (t < 11) {
            const int col = (t + 1) * 64;
            #pragma unroll
            for (int kk2 = 0; kk2 < 2; ++kk2) {
                rA[kk2 * 4 + 0] = *(const float4*)(a0 + col + kk2 * 32);
                rA[kk2 * 4 + 1] = *(const float4*)(a0 + col + kk2 * 32 + 4);
                rA[kk2 * 4 + 2] = *(const float4*)(a1 + col + kk2 * 32);
                rA[kk2 * 4 + 3] = *(const float4*)(a1 + col + kk2 * 32 + 4);
            }
        }
        // (4) compute phase t from buf[t&1] (conflict-free lane-contiguous ds_read_b128)
        const unsigned short* bbase = smem + (t & 1) * 16384;
        #pragma unroll
        for (int kk2 = 0; kk2 < 2; ++kk2) {
            #pragma unroll
            for (int j = 0; j < 16; ++j) {
                const bf16x8 b = *(const bf16x8*)(bbase + ((kk2 * 16 + j) * 64 + lane) * 8);
                acc[0][j] = __builtin_amdgcn_mfma_f32_16x16x32_bf16(af[kk2 * 2 + 0], b, acc[0][j], 0, 0, 0);
                acc[1][j] = __builtin_amdgcn_mfma_f32_16x16x32_bf16(af[kk2 * 2 + 1], b, acc[1][j], 0, 0, 0);
            }
        }
        // (5) counted drain: stage(t+1) done (buf ready); A(t+1) stays in flight
        if (t < 11) {
            asm volatile("s_waitcnt vmcnt(8)" ::: "memory");
        } else {
            asm volatile("s_waitcnt vmcnt(0)" ::: "memory");
        }
        __builtin_amdgcn_s_barrier();
    }

    // ---- epilogue: XOR-swizzled LDS transpose -> 512 B/row coalesced bf16 stores ----
    // write (row, col j*16+l15) at physical col group (j^quad): row stride 512 B == 0 mod 32
    // banks, so quad XOR spreads the 4 quads across all 32 banks (2 lanes/bank = free).
    #pragma unroll
    for (int i = 0; i < 2; ++i)
        #pragma unroll
        for (int j = 0; j < 16; ++j)
            #pragma unroll
            for (int rr = 0; rr < 4; ++rr)
                smem[(w * 32 + i * 16 + quad * 4 + rr) * 256 + ((j ^ quad) * 16 + l15)] =
                    f2bf(acc[i][j][rr]);
    __syncthreads();

    const int orow = tid >> 3;          // 0..31
    const int ou   = tid & 7;           // 8 lanes x 64 B = 512 B per row
    #pragma unroll
    for (int rb = 0; rb < 4; ++rb) {
        const int row = orow + rb * 32;
        const int rq  = (row >> 2) & 3;               // quad that wrote this row
        const unsigned short* srcrow = smem + row * 256;
        unsigned short* dst = Cb + (size_t)(m0 + row) * NCOLS + ou * 32;
        #pragma unroll
        for (int q = 0; q < 4; ++q) {
            const int off = (ou * 32 + q * 8) ^ (rq * 16);   // 16B-aligned inverse swizzle
            *(uint4*)(dst + q * 8) = *(const uint4*)(srcrow + off);
        }
    }
}

// ---------------- kernel 2: gather-mean, block per (batch, patch-row h) ----------------
// LDS staging with bank-rotated padded strides; inner compute via ds_read_b128 (4 per 8-pixel task).
#define CSTRG 280   // sCur row stride (shorts): 560 B -> lane bank-start 12*wg mod 32 (full spread)
#define PSTRG 152   // sPrevHi row stride: 304 B -> same rotation
__global__ __launch_bounds__(256, 2) void gather_kernel(const unsigned short* __restrict__ proj,
                                                        float* __restrict__ out) {
    __shared__ unsigned short sCur[64 * CSTRG];     // 35840 B
    __shared__ unsigned short sPrevHi[64 * PSTRG];  // 19456 B

    const int blk = blockIdx.x;          // b*64 + h
    const int b   = blk >> 6;
    const int h   = blk & 63;
    const int tid = threadIdx.x;
    const unsigned short* base = proj + (size_t)b * (NPATCH * NCOLS);

    const uint4* gCur = (const uint4*)(base + (size_t)h * 64 * 256);
    #pragma unroll
    for (int p = 0; p < 8; ++p) {
        const int i = tid + p * 256;     // 2048 uint4: patch = i>>5, q = i&31
        *(uint4*)(sCur + (i >> 5) * CSTRG + (i & 31) * 8) = gCur[i];
    }
    if (h > 0) {
        const uint4* gPrev = (const uint4*)(base + (size_t)(h - 1) * 64 * 256);
        #pragma unroll
        for (int p = 0; p < 4; ++p) {
            const int i = tid + p * 256; // 1024 uint4: patch = i>>4, hi-half q = i&15
            *(uint4*)(sPrevHi + (i >> 4) * PSTRG + (i & 15) * 8) = gPrev[(i >> 4) * 32 + 16 + (i & 15)];
        }
    }
    __syncthreads();

    const float fch_base = (h == 0) ? 1.f : 0.5f;

    #pragma unroll
    for (int t = 0; t < 2; ++t) {
        const int task = tid + t * 256;  // r = task>>6 (wave-uniform), wg = lane
        const int r  = task >> 6;
        const int wg = task & 63;
        const int ph = h * 8 + r;

        float s[8] = {0.f, 0.f, 0.f, 0.f, 0.f, 0.f, 0.f, 0.f};
        auto addq = [&](uint4 v) {
            const unsigned int u[4] = {v.x, v.y, v.z, v.w};
            #pragma unroll
            for (int q = 0; q < 4; ++q) {
                s[2 * q]     += bf2f(u[q] & 0xFFFFu);
                s[2 * q + 1] += bf2f(u[q] >> 16);
            }
        };
        auto sumq = [&](uint4 v) -> float {
            const unsigned int u[4] = {v.x, v.y, v.z, v.w};
            float e = 0.f;
            #pragma unroll
            for (int q = 0; q < 4; ++q) e += bf2f(u[q] & 0xFFFFu) + bf2f(u[q] >> 16);
            return e;
        };

        addq(*(const uint4*)(sCur + wg * CSTRG + r * 16));                       // cur(h,wg) dw 0..7
        if (wg > 0) addq(*(const uint4*)(sCur + (wg - 1) * CSTRG + r * 16 + 8)); // cur(h,wg-1) dw 8..15
        if (h > 0) {
            addq(*(const uint4*)(sPrevHi + wg * PSTRG + r * 16));                // prev dh=r+8
            if (wg > 0) addq(*(const uint4*)(sPrevHi + (wg - 1) * PSTRG + r * 16 + 8));
        }
        if (wg == 63) {                   // w-clamp extras -> pixel 511 only
            s[7] += sumq(*(const uint4*)(sCur + 63 * CSTRG + r * 16 + 8));
            if (h > 0) s[7] += sumq(*(const uint4*)(sPrevHi + 63 * PSTRG + r * 16 + 8));
        }
        float fch = fch_base;
        if (ph == 511) {                  // h-clamp extras: dh 8..15 of cur patch-row 63
            fch = 0.1f;
            #pragma unroll 1
            for (int dh = 8; dh < 16; ++dh) {
                addq(*(const uint4*)(sCur + wg * CSTRG + dh * 16));
                if (wg > 0) addq(*(const uint4*)(sCur + (wg - 1) * CSTRG + dh * 16 + 8));
                if (wg == 63) s[7] += sumq(*(const uint4*)(sCur + 63 * CSTRG + dh * 16 + 8));
            }
        }

        const float fcw = (wg == 0) ? 1.f : 0.5f;
        float f7 = fcw;
        if (wg == 63) f7 = 0.1f;
        float* orow = out + ((size_t)(b * 512 + ph)) * 512 + wg * 8;
        *(float4*)orow       = make_float4(s[0] * fch * fcw, s[1] * fch * fcw,
                                           s[2] * fch * fcw, s[3] * fch * fcw);
        *(float4*)(orow + 4) = make_float4(s[4] * fch * fcw, s[5] * fch * fcw,
                                           s[6] * fch * fcw, s[7] * fch * f7);
    }
}

extern "C" void kernel_launch(void* const* d_in, const int* in_sizes, int n_in,
                              void* d_out, int out_size, void* d_ws, size_t ws_size,
                              hipStream_t stream) {
    const float* tgt    = (const float*)d_in[0];   // [16,4096,768] fp32
    const float* weight = (const float*)d_in[1];   // [16,16,768]  fp32
    float* out = (float*)d_out;                    // [16,512,512] fp32

    unsigned short* proj = (unsigned short*)d_ws;                                      // 32 MB bf16
    unsigned short* wf   = (unsigned short*)((char*)d_ws + (size_t)MROWS * NCOLS * 2); // +384 KB fragments

    wpack_kernel<<<96, 256, 0, stream>>>(weight, wf);               // 24576 threads
    gemm_kernel<<<MROWS / 128, 256, 0, stream>>>(tgt, wf, proj);    // 512 blocks
    gather_kernel<<<BATCH * 64, 256, 0, stream>>>(proj, out);       // 1024 blocks
}